// Round 9
// baseline (92.464 us; speedup 1.0000x reference)
//
#include <hip/hip_runtime.h>
#include <math.h>

#define D 128
#define G 256

// ws layout:
//   [0,      512)           u  (128 f32) = Wp @ We[0:G]
//   [512,    516)           c  (scalar)  = bp . We[0:G]
//   [1024,   1024+4B)       s[B]    per-graph gated sums
//   [65536,  65536+4B)      pg[B]   hv[last_idx[g]] . we2
//   [131072, 131072+4B)     s2[B]   dead scratch (diagnostic dup dispatch)
//   [196608, 196608+4B)     pg2[B]  dead scratch (diagnostic dup dispatch)

// DPP-based add of a permuted copy (VALU pipe, no LDS/DS traffic).
template <int CTRL>
__device__ __forceinline__ float dpp_add(float x) {
    int yi = __builtin_amdgcn_update_dpp(0, __float_as_int(x), CTRL, 0xf, 0xf, true);
    return x + __int_as_float(yi);
}

// Direction-free 16-lane row sum: quad xor1, quad xor2, half-row mirror
// (adds the other quad of the 8-half), full-row mirror (adds the other
// 8-half). Every lane of each 16-lane row ends with the full row sum.
__device__ __forceinline__ float row16_sum_all(float x) {
    x = dpp_add<0xB1>(x);     // quad_perm [1,0,3,2]
    x = dpp_add<0x4E>(x);     // quad_perm [2,3,0,1]
    x = dpp_add<0x141>(x);    // row_half_mirror
    x = dpp_add<0x140>(x);    // row_mirror
    return x;
}

// One 64-lane wave per block, role by blockIdx.x:
//   [0,128)          : u[b] = Wp[b,:] . We[0:256]
//   128              : c = bp . We[0:256]
//   [129, 129+nzero) : zero s (float4 stores)
__global__ void prep_kernel(const float* __restrict__ Wp,
                            const float* __restrict__ bp,
                            const float* __restrict__ We,
                            float* __restrict__ u,
                            float* __restrict__ c,
                            float* __restrict__ s,
                            int B) {
    int b    = blockIdx.x;
    int lane = threadIdx.x;   // 0..63

    if (b < 129) {
        const float* row = (b < D) ? (Wp + (size_t)b * G) : bp;
        float4 rv = ((const float4*)row)[lane];
        float4 wv = ((const float4*)We)[lane];
        float p = rv.x * wv.x + rv.y * wv.y + rv.z * wv.z + rv.w * wv.w;
        #pragma unroll
        for (int m = 32; m >= 1; m >>= 1) p += __shfl_xor(p, m, 64);
        if (lane == 0) {
            if (b < D) u[b] = p;
            else       *c  = p;
        }
        return;
    }
    int idx4 = (b - 129) * 64 + lane;            // float4 index into s
    if (idx4 * 4 + 3 < B) ((float4*)s)[idx4] = make_float4(0.f, 0.f, 0.f, 0.f);
    else {
        for (int j = idx4 * 4; j < B; ++j) s[j] = 0.f;   // tail (no-op if B%4==0)
    }
}

// Exactly nblocks streaming blocks (8192 waves = one full residency round).
// 16 lanes per row, 4 rows per wave-iteration. Lane lj of each 16-group
// covers columns [4lj,4lj+4) and [64+4lj,64+4lj+4) -> two fully-coalesced
// float4 loads per lane per iter (2 KB in flight per wave). Reduce is pure
// DPP (no DS traffic), direction-free, result in all 16 lanes. seg_ids is
// sorted; each 16-group's leader (lj==0) tracks its stride-4 row subsequence
// with a running (cur, acc) and flushes one atomicAdd per segment change.
// After streaming, each wave gathers 4 graphs: pg[g] = hv[last_idx[g]].we2.
// Assumes N % 4 == 0 (N = 500000).
__global__ __launch_bounds__(256, 8)
void node_kernel(const float* __restrict__ hv,
                 const float* __restrict__ Wg,
                 const float* __restrict__ bg,
                 const int*   __restrict__ seg_ids,
                 const float* __restrict__ u,
                 const float* __restrict__ cptr,
                 const float* __restrict__ We,
                 const int*   __restrict__ last_idx,
                 float*       __restrict__ s,
                 float*       __restrict__ pg,
                 int N, int B, int chunk, int nwaves) {
    int tid  = blockIdx.x * blockDim.x + threadIdx.x;
    int wave = tid >> 6;
    int lane = threadIdx.x & 63;
    int grp  = lane >> 4;   // row offset within the 4-row iter
    int lj   = lane & 15;   // lane within 16-group

    const float4* hv4 = (const float4*)hv;

    int start = wave * chunk;
    if (start < N) {
        int end = min(start + chunk, N);   // start, end multiples of 4

        float4 wgLo = ((const float4*)Wg)[lj];
        float4 wgHi = ((const float4*)Wg)[16 + lj];
        float4 uLo  = ((const float4*)u)[lj];
        float4 uHi  = ((const float4*)u)[16 + lj];
        float  bgv  = *bg;
        float  cv   = *cptr;

        int   cur = -1;
        float acc = 0.f;

        for (int r0 = start; r0 < end; r0 += 4) {
            int row = r0 + grp;
            const float4* rp = hv4 + (size_t)row * 32;
            float4 vLo = rp[lj];
            float4 vHi = rp[16 + lj];
            int seg = seg_ids[row];          // uniform within each 16-group

            float p1 = vLo.x*wgLo.x + vLo.y*wgLo.y + vLo.z*wgLo.z + vLo.w*wgLo.w
                     + vHi.x*wgHi.x + vHi.y*wgHi.y + vHi.z*wgHi.z + vHi.w*wgHi.w;
            float p2 = vLo.x*uLo.x + vLo.y*uLo.y + vLo.z*uLo.z + vLo.w*uLo.w
                     + vHi.x*uHi.x + vHi.y*uHi.y + vHi.z*uHi.z + vHi.w*uHi.w;
            p1 = row16_sum_all(p1);
            p2 = row16_sum_all(p2);
            float gate = 1.f / (1.f + __expf(-(p1 + bgv)));
            float val  = gate * (p2 + cv);

            if (lj == 0) {
                if (seg != cur) {
                    if (cur >= 0) atomicAdd(&s[cur], acc);
                    cur = seg;
                    acc = val;
                } else {
                    acc += val;
                }
            }
        }
        if (lj == 0 && cur >= 0) atomicAdd(&s[cur], acc);
    }

    // gather tail: 4 graphs per wave-iter (B % 4 == 0)
    float4 w2Lo = ((const float4*)We)[64 + lj];        // we2 = We[256:384]
    float4 w2Hi = ((const float4*)We)[64 + 16 + lj];
    for (int g0 = wave * 4; g0 < B; g0 += nwaves * 4) {
        int g = g0 + grp;
        int row = last_idx[g];
        const float4* rp = hv4 + (size_t)row * 32;
        float4 vLo = rp[lj];
        float4 vHi = rp[16 + lj];
        float p = vLo.x*w2Lo.x + vLo.y*w2Lo.y + vLo.z*w2Lo.z + vLo.w*w2Lo.w
                + vHi.x*w2Hi.x + vHi.y*w2Hi.y + vHi.z*w2Hi.z + vHi.w*w2Hi.w;
        p = row16_sum_all(p);
        if (lj == 0) pg[g] = p;
    }
}

// One thread per graph: logit = s[g] + pg[g] + be, stable log-sigmoid + select.
__global__ void final_kernel(const float* __restrict__ s,
                             const float* __restrict__ pg,
                             const float* __restrict__ be,
                             const int*   __restrict__ a,
                             float*       __restrict__ out,
                             int B) {
    int g = blockIdx.x * blockDim.x + threadIdx.x;
    if (g >= B) return;
    float logit = s[g] + pg[g] + *be;
    float x = (a[g] != 0) ? logit : -logit;       // log_probs[:, a]
    // log_sigmoid(x) = min(x,0) - log1p(exp(-|x|))
    out[g] = fminf(x, 0.f) - log1pf(__expf(-fabsf(x)));
}

extern "C" void kernel_launch(void* const* d_in, const int* in_sizes, int n_in,
                              void* d_out, int out_size, void* d_ws, size_t ws_size,
                              hipStream_t stream) {
    const float* hv       = (const float*)d_in[0];
    const float* Wg       = (const float*)d_in[1];
    const float* bg       = (const float*)d_in[2];
    const float* Wp       = (const float*)d_in[3];
    const float* bp       = (const float*)d_in[4];
    const float* We       = (const float*)d_in[5];
    const float* be       = (const float*)d_in[6];
    const int*   seg_ids  = (const int*)d_in[7];
    const int*   last_idx = (const int*)d_in[8];
    const int*   a        = (const int*)d_in[9];
    float*       out      = (float*)d_out;

    int N = in_sizes[0] / D;
    int B = in_sizes[8];

    float* u   = (float*)d_ws;
    float* c   = (float*)((char*)d_ws + 512);
    float* s   = (float*)((char*)d_ws + 1024);
    float* pg  = (float*)((char*)d_ws + 65536);
    float* s2  = (float*)((char*)d_ws + 131072);   // dead (diagnostic)
    float* pg2 = (float*)((char*)d_ws + 196608);   // dead (diagnostic)

    // prep: 129 weight blocks + zero-s blocks
    int nzero = (B / 4 + 63) / 64;
    prep_kernel<<<129 + nzero, 64, 0, stream>>>(Wp, bp, We, u, c, s, B);

    const int nblocks = 2048;                 // 8192 waves = one residency round
    int nwaves = nblocks * 256 / 64;
    int chunk = (N + nwaves - 1) / nwaves;
    chunk = (chunk + 3) & ~3;                 // multiple of 4 (4 rows per iter)

    // DIAGNOSTIC duplicate dispatch into dead scratch: total_R9 - total_R7
    // isolates one warm node's duration (HBM-bound ~40 vs L3-served ~20-28).
    node_kernel<<<nblocks, 256, 0, stream>>>(
        hv, Wg, bg, seg_ids, u, c, We, last_idx, s2, pg2, N, B, chunk, nwaves);

    node_kernel<<<nblocks, 256, 0, stream>>>(
        hv, Wg, bg, seg_ids, u, c, We, last_idx, s, pg, N, B, chunk, nwaves);

    int fblocks = (B + 255) / 256;
    final_kernel<<<fblocks, 256, 0, stream>>>(s, pg, be, a, out, B);
}

// Round 10
// 51.344 us; speedup vs baseline: 1.8009x; 1.8009x over previous
//
#include <hip/hip_runtime.h>
#include <math.h>

#define D 128
#define G 256

// ws layout:
//   [0,      512)       u  (128 f32) = Wp @ We[0:G]
//   [512,    516)       c  (scalar)  = bp . We[0:G]
//   [1024,   1024+4B)   s[B]    per-graph gated sums
//   [65536,  65536+4B)  pg[B]   hv[last_idx[g]] . we2

// DPP-based add of a permuted copy (VALU pipe, no LDS/DS traffic).
template <int CTRL>
__device__ __forceinline__ float dpp_add(float x) {
    int yi = __builtin_amdgcn_update_dpp(0, __float_as_int(x), CTRL, 0xf, 0xf, true);
    return x + __int_as_float(yi);
}

// Direction-free 16-lane row sum: quad xor1, quad xor2, half-row mirror,
// full-row mirror. Every lane of each 16-lane row ends with the row sum.
__device__ __forceinline__ float row16_sum_all(float x) {
    x = dpp_add<0xB1>(x);     // quad_perm [1,0,3,2]
    x = dpp_add<0x4E>(x);     // quad_perm [2,3,0,1]
    x = dpp_add<0x141>(x);    // row_half_mirror
    x = dpp_add<0x140>(x);    // row_mirror
    return x;
}

// One 64-lane wave per block, role by blockIdx.x:
//   [0,128)          : u[b] = Wp[b,:] . We[0:256]
//   128              : c = bp . We[0:256]
//   [129, 129+nzero) : zero s (float4 stores)
__global__ void prep_kernel(const float* __restrict__ Wp,
                            const float* __restrict__ bp,
                            const float* __restrict__ We,
                            float* __restrict__ u,
                            float* __restrict__ c,
                            float* __restrict__ s,
                            int B) {
    int b    = blockIdx.x;
    int lane = threadIdx.x;   // 0..63

    if (b < 129) {
        const float* row = (b < D) ? (Wp + (size_t)b * G) : bp;
        float4 rv = ((const float4*)row)[lane];
        float4 wv = ((const float4*)We)[lane];
        float p = rv.x * wv.x + rv.y * wv.y + rv.z * wv.z + rv.w * wv.w;
        #pragma unroll
        for (int m = 32; m >= 1; m >>= 1) p += __shfl_xor(p, m, 64);
        if (lane == 0) {
            if (b < D) u[b] = p;
            else       *c  = p;
        }
        return;
    }
    int idx4 = (b - 129) * 64 + lane;            // float4 index into s
    if (idx4 * 4 + 3 < B) ((float4*)s)[idx4] = make_float4(0.f, 0.f, 0.f, 0.f);
    else {
        for (int j = idx4 * 4; j < B; ++j) s[j] = 0.f;   // tail (no-op if B%4==0)
    }
}

// Exactly nblocks streaming blocks (8192 waves = one full residency round).
// 16 lanes per row, 4 rows (one quad) per wave-iteration. Lane lj of each
// 16-group covers columns [4lj,4lj+4) and [64+4lj,64+4lj+4) -> two fully-
// coalesced float4 loads per lane per iter. Reduce is pure DPP (no DS
// traffic); result lands in all 16 lanes. seg_ids is sorted; each 16-group's
// leader (lj==0) keeps a running (cur, acc) over its stride-4 row
// subsequence and flushes one atomicAdd per segment change.
// Work assignment: balanced quad partition — wave w owns quads
// [w*nquads/nwaves, (w+1)*nquads/nwaves); all waves get 15-16 quads, none
// idle. Only the last quad of the last wave can be partial (row<N guard,
// uniform per 16-group).
// After streaming, the first B/4 waves gather pg[g] = hv[last_idx[g]].we2.
__global__ __launch_bounds__(256, 8)
void node_kernel(const float* __restrict__ hv,
                 const float* __restrict__ Wg,
                 const float* __restrict__ bg,
                 const int*   __restrict__ seg_ids,
                 const float* __restrict__ u,
                 const float* __restrict__ cptr,
                 const float* __restrict__ We,
                 const int*   __restrict__ last_idx,
                 float*       __restrict__ s,
                 float*       __restrict__ pg,
                 int N, int B, int nquads, int nwaves) {
    int tid  = blockIdx.x * blockDim.x + threadIdx.x;
    int wave = tid >> 6;
    int lane = threadIdx.x & 63;
    int grp  = lane >> 4;   // row offset within the quad
    int lj   = lane & 15;   // lane within 16-group

    const float4* hv4 = (const float4*)hv;

    int q0 = (int)(((long long)wave * nquads) / nwaves);
    int q1 = (int)(((long long)(wave + 1) * nquads) / nwaves);

    if (q0 < q1) {
        float4 wgLo = ((const float4*)Wg)[lj];
        float4 wgHi = ((const float4*)Wg)[16 + lj];
        float4 uLo  = ((const float4*)u)[lj];
        float4 uHi  = ((const float4*)u)[16 + lj];
        float  bgv  = *bg;
        float  cv   = *cptr;

        int   cur = -1;
        float acc = 0.f;

        for (int r0 = q0 * 4; r0 < q1 * 4; r0 += 4) {
            int row = r0 + grp;
            if (row < N) {                   // uniform per 16-group; false only
                                             // in the last wave's last quad
                const float4* rp = hv4 + (size_t)row * 32;
                float4 vLo = rp[lj];
                float4 vHi = rp[16 + lj];
                int seg = seg_ids[row];      // uniform within the 16-group

                float p1 = vLo.x*wgLo.x + vLo.y*wgLo.y + vLo.z*wgLo.z + vLo.w*wgLo.w
                         + vHi.x*wgHi.x + vHi.y*wgHi.y + vHi.z*wgHi.z + vHi.w*wgHi.w;
                float p2 = vLo.x*uLo.x + vLo.y*uLo.y + vLo.z*uLo.z + vLo.w*uLo.w
                         + vHi.x*uHi.x + vHi.y*uHi.y + vHi.z*uHi.z + vHi.w*uHi.w;
                p1 = row16_sum_all(p1);
                p2 = row16_sum_all(p2);
                float gate = 1.f / (1.f + __expf(-(p1 + bgv)));
                float val  = gate * (p2 + cv);

                if (lj == 0) {
                    if (seg != cur) {
                        if (cur >= 0) atomicAdd(&s[cur], acc);
                        cur = seg;
                        acc = val;
                    } else {
                        acc += val;
                    }
                }
            }
        }
        if (lj == 0 && cur >= 0) atomicAdd(&s[cur], acc);
    }

    // gather tail: 4 graphs per wave (first B/4 waves), B % 4 == 0
    float4 w2Lo = ((const float4*)We)[64 + lj];        // we2 = We[256:384]
    float4 w2Hi = ((const float4*)We)[64 + 16 + lj];
    for (int g0 = wave * 4; g0 < B; g0 += nwaves * 4) {
        int g = g0 + grp;
        int row = last_idx[g];
        const float4* rp = hv4 + (size_t)row * 32;
        float4 vLo = rp[lj];
        float4 vHi = rp[16 + lj];
        float p = vLo.x*w2Lo.x + vLo.y*w2Lo.y + vLo.z*w2Lo.z + vLo.w*w2Lo.w
                + vHi.x*w2Hi.x + vHi.y*w2Hi.y + vHi.z*w2Hi.z + vHi.w*w2Hi.w;
        p = row16_sum_all(p);
        if (lj == 0) pg[g] = p;
    }
}

// One thread per graph: logit = s[g] + pg[g] + be, stable log-sigmoid + select.
__global__ void final_kernel(const float* __restrict__ s,
                             const float* __restrict__ pg,
                             const float* __restrict__ be,
                             const int*   __restrict__ a,
                             float*       __restrict__ out,
                             int B) {
    int g = blockIdx.x * blockDim.x + threadIdx.x;
    if (g >= B) return;
    float logit = s[g] + pg[g] + *be;
    float x = (a[g] != 0) ? logit : -logit;       // log_probs[:, a]
    // log_sigmoid(x) = min(x,0) - log1p(exp(-|x|))
    out[g] = fminf(x, 0.f) - log1pf(__expf(-fabsf(x)));
}

extern "C" void kernel_launch(void* const* d_in, const int* in_sizes, int n_in,
                              void* d_out, int out_size, void* d_ws, size_t ws_size,
                              hipStream_t stream) {
    const float* hv       = (const float*)d_in[0];
    const float* Wg       = (const float*)d_in[1];
    const float* bg       = (const float*)d_in[2];
    const float* Wp       = (const float*)d_in[3];
    const float* bp       = (const float*)d_in[4];
    const float* We       = (const float*)d_in[5];
    const float* be       = (const float*)d_in[6];
    const int*   seg_ids  = (const int*)d_in[7];
    const int*   last_idx = (const int*)d_in[8];
    const int*   a        = (const int*)d_in[9];
    float*       out      = (float*)d_out;

    int N = in_sizes[0] / D;
    int B = in_sizes[8];

    float* u  = (float*)d_ws;
    float* c  = (float*)((char*)d_ws + 512);
    float* s  = (float*)((char*)d_ws + 1024);
    float* pg = (float*)((char*)d_ws + 65536);

    // prep: 129 weight blocks + zero-s blocks
    int nzero = (B / 4 + 63) / 64;
    prep_kernel<<<129 + nzero, 64, 0, stream>>>(Wp, bp, We, u, c, s, B);

    // node: exactly one residency round (8 blocks/CU x 256 CU)
    const int nblocks = 2048;
    int nwaves = nblocks * 256 / 64;          // 8192
    int nquads = (N + 3) / 4;                 // balanced quad partition
    node_kernel<<<nblocks, 256, 0, stream>>>(
        hv, Wg, bg, seg_ids, u, c, We, last_idx, s, pg, N, B, nquads, nwaves);

    int fblocks = (B + 255) / 256;
    final_kernel<<<fblocks, 256, 0, stream>>>(s, pg, be, a, out, B);
}